// Round 19
// baseline (225.963 us; speedup 1.0000x reference)
//
#include <hip/hip_runtime.h>

#define NUM_IDS 65
#define EDIM 32
#define NSUM (NUM_IDS * EDIM)      // 2080
#define NTOT (NSUM + NUM_IDS)      // 2145
#define LPAD 33                    // mean tile row pad
#define R36 36                     // k1 accum row: 32 sums + count + pad, 144B (16B aligned)
#define CP (NUM_IDS * R36)         // 2340 floats per wave copy

// ws float offsets
#define WS_SUMS    0               // 2145 (2080 sums then 65 counts)
#define WS_PULLACC 2148
#define WS_PART    2176            // [nb1][NTOT]

// pure-VALU cross-lane permute
#define DPPI(x, ctrl) __builtin_amdgcn_update_dpp(0, (x), (ctrl), 0xF, 0xF, true)
// ctrl: 0xB1 quad[1,0,3,2] (^1) | 0x4E quad[2,3,0,1] (^2) | 0x124 row_ror:4

__device__ __forceinline__ void gload4(const float4* p, float4& d) {
    asm volatile("global_load_dwordx4 %0, %1, off" : "=v"(d) : "v"(p));
}
__device__ __forceinline__ void gload1(const int* p, int& d) {
    asm volatile("global_load_dword %0, %1, off" : "=v"(d) : "v"(p));
}
__device__ __forceinline__ void waitN() {      // allow 4 newest loads in flight
    asm volatile("s_waitcnt vmcnt(4)" ::: "memory");
    __builtin_amdgcn_sched_barrier(0);         // rule #18: no hoisting past the wait
}
__device__ __forceinline__ void wait0() {
    asm volatile("s_waitcnt vmcnt(0)" ::: "memory");
    __builtin_amdgcn_sched_barrier(0);
}

__global__ void k0_zero(float* __restrict__ ws) {
    int i = blockIdx.x * 256 + threadIdx.x;
    if (i < NTOT) ws[WS_SUMS + i] = 0.f;
    if (i == 0) ws[WS_PULLACC] = 0.f;
}

// Pass 1 (r13 form, measured ~46us warm): wave-private LDS segment reduction.
__global__ __launch_bounds__(256) void k1_reduce(const float4* __restrict__ emb4,
                                                 const int* __restrict__ lab,
                                                 float* __restrict__ ws,
                                                 int M, int nb1, int nit, int atomic_mode) {
    __shared__ float ls[4 * CP];               // 36.6 KB -> 4 blocks/CU
    const int t = threadIdx.x;
    const int wave = t >> 6, lane = t & 63;
    const int s = lane & 7;                    // point slot
    const int c = lane >> 3;                   // float4 chunk (dims 4c..4c+3)
    float* my = ls + wave * CP;
    for (int j = t; j < 4 * CP; j += 256) ls[j] = 0.f;
    __syncthreads();

    const long Mm1 = (long)M - 1;
    const long STR = (long)nb1 * 32;
    const long p0 = (long)blockIdx.x * 32 + wave * 8 + s;
    const int lp1 = lane + 1;
    int cntreg = 0;
    const int negkey = -64 - s;
    const int e1 = (s ^ 1) < s, e2 = (s ^ 2) < s, e3 = (s ^ 3) < s,
              e4 = (s ^ 4) < s, e5 = (s ^ 5) < s, e6 = (s ^ 6) < s, e7 = (s ^ 7) < s;

    auto ISSUE = [&](int j, int& L, float4& v) {
        long p = p0 + (long)j * STR;
        long pc = p < Mm1 ? p : Mm1;           // clamp: asm loads have no bounds check
        gload1(lab + pc, L);
        gload4(emb4 + pc * 8 + c, v);
    };
    auto PROC = [&](int j, int L, float4 v) {
        const bool inb = (p0 + (long)j * STR) < (long)M;
        const bool act = inb && (L > 0);
        int x0 = act ? L : negkey;             // unique negatives never collide
        int x1 = DPPI(x0, 0xB1);               // key(s^1)
        int x2 = DPPI(x0, 0x4E);               // key(s^2)
        int x3 = DPPI(x1, 0x4E);               // key(s^3)
        int x4 = DPPI(x0, 0x124);              // key(s^4): keys are 8-periodic in lane
        int x5 = DPPI(x1, 0x124);              // key(s^5)
        int x6 = DPPI(x2, 0x124);              // key(s^6)
        int x7 = DPPI(x3, 0x124);              // key(s^7)
        cntreg += (x0 == lp1) + (x1 == lp1) + (x2 == lp1) + (x3 == lp1)
                + (x4 == lp1) + (x5 == lp1) + (x6 == lp1) + (x7 == lp1);
        int ne = (e1 & (x1 == x0)) + (e2 & (x2 == x0)) + (e3 & (x3 == x0))
               + (e4 & (x4 == x0)) + (e5 & (x5 == x0)) + (e6 & (x6 == x0))
               + (e7 & (x7 == x0));            // # earlier slots with same label
        const int off = (act ? L : 0) * R36 + c * 4;
        if (act && ne == 0) {
            float4 o = *(float4*)(my + off);
            o.x += v.x; o.y += v.y; o.z += v.z; o.w += v.w;
            *(float4*)(my + off) = o;
        }
        if (__ballot(act && ne > 0)) {         // rare duplicate labels
            #pragma unroll 1
            for (int r = 1; r < 8; ++r) {
                if (!__ballot(act && ne == r)) break;
                if (act && ne == r) {          // in-order DS sees round r-1 write
                    float4 o = *(float4*)(my + off);
                    o.x += v.x; o.y += v.y; o.z += v.z; o.w += v.w;
                    *(float4*)(my + off) = o;
                }
            }
        }
    };

    int LA, LB, LC; float4 VA, VB, VC;
    ISSUE(0, LA, VA); ISSUE(1, LB, VB);
    for (int i = 0; i < nit; i += 3) {         // nit is a multiple of 3
        ISSUE(i + 2, LC, VC); waitN(); PROC(i, LA, VA);
        ISSUE(i + 3, LA, VA); waitN(); PROC(i + 1, LB, VB);
        ISSUE(i + 4, LB, VB); waitN(); PROC(i + 2, LC, VC);
    }
    wait0();

    my[lp1 * R36 + 32] += (float)cntreg;       // register counts -> rows 1..64
    __syncthreads();

    for (int j = t; j < NTOT; j += 256) {      // combine 4 wave copies
        int off = (j < NSUM) ? ((j >> 5) * R36 + (j & 31))
                             : ((j - NSUM) * R36 + 32);
        float v = ls[off] + ls[CP + off] + ls[2 * CP + off] + ls[3 * CP + off];
        if (atomic_mode) {
            if (v != 0.f) atomicAdd(&ws[WS_SUMS + j], v);
        } else {
            ws[WS_PART + (size_t)blockIdx.x * NTOT + j] = v;
        }
    }
}

// Reduce per-block partials -> SUMS; block 0 zeroes the pull accumulator.
// Idempotent (pure overwrite) -> tripled this round for measurement.
__global__ __launch_bounds__(256) void k2_reduce_partials(float* __restrict__ ws, int nb1) {
    const int t = threadIdx.x;
    const int jl = t & 31, bl = t >> 5;
    const int j = blockIdx.x * 32 + jl;
    const float* part = ws + WS_PART;
    float acc = 0.f;
    if (j < NTOT)
        for (int b = bl; b < nb1; b += 8) acc += part[(size_t)b * NTOT + j];
    __shared__ float red[256];
    red[t] = acc;
    __syncthreads();
    for (int sd = 128; sd >= 32; sd >>= 1) {
        if (t < sd) red[t] += red[t + sd];
        __syncthreads();
    }
    if (t < 32) {
        int jj = blockIdx.x * 32 + t;
        if (jj < NTOT) ws[WS_SUMS + jj] = red[t];
    }
    if (blockIdx.x == 0 && t == 0) ws[WS_PULLACC] = 0.f;
}

// Pass 2 (r8 loop form, measured ~60us): builds means+coef locally from SUMS.
__global__ __launch_bounds__(256) void k4_pull(const float4* __restrict__ emb4,
                                               const int* __restrict__ lab,
                                               float* __restrict__ ws,
                                               int M, int nb4) {
    __shared__ float lmean[NUM_IDS * LPAD];
    __shared__ float lcoef[NUM_IDS];
    __shared__ float lpull[NUM_IDS];
    __shared__ float red[NUM_IDS];
    const int t = threadIdx.x;
    for (int j = t; j < NSUM; j += 256) {
        int cc = j >> 5;
        lmean[cc * LPAD + (j & 31)] = ws[WS_SUMS + j] / fmaxf(ws[WS_SUMS + NSUM + cc], 1.f);
    }
    if (t < NUM_IDS) {
        float cv = ws[WS_SUMS + NSUM + t];
        lcoef[t] = (t > 0 && cv > 0.f) ? (1.f / fmaxf(cv, 1.f)) : 0.f;
        lpull[t] = 0.f;
    }
    __syncthreads();

    const int c = t & 7;
    const long stride = (long)nb4 * 32;
    const long start = (long)blockIdx.x * 32 + (t >> 3);

    auto LD = [&](long p, int& L, float4& v) {
        if (p < M) { L = lab[p]; v = emb4[p * 8 + c]; }
        else       { L = 0; v = make_float4(0.f, 0.f, 0.f, 0.f); }
    };
    auto PR = [&](int L, float4 v) {
        float d2 = 0.f;
        if (L > 0) {
            int bse = L * LPAD + c * 4;
            float dx = v.x - lmean[bse + 0];
            float dy = v.y - lmean[bse + 1];
            float dz = v.z - lmean[bse + 2];
            float dw = v.w - lmean[bse + 3];
            d2 = dx * dx + dy * dy + dz * dz + dw * dw;
        }
        d2 += __shfl_xor(d2, 1);
        d2 += __shfl_xor(d2, 2);
        d2 += __shfl_xor(d2, 4);
        if (c == 0 && L > 0 && d2 > 0.f) {
            float dist = sqrtf(d2);
            float h = fmaxf(dist - 0.5f, 0.f);   // DELTA_PULL
            atomicAdd(&lpull[L], h * h);
        }
    };

    int L0, L1;
    float4 v0, v1;
    long pA = start;
    LD(pA, L0, v0);
    while (pA < M) {
        const long pB = pA + stride;
        LD(pB, L1, v1);
        PR(L0, v0);
        const long pA2 = pB + stride;
        LD(pA2, L0, v0);
        PR(L1, v1);
        pA = pA2;
    }
    __syncthreads();
    if (t < NUM_IDS) red[t] = lpull[t] * lcoef[t];
    __syncthreads();
    if (t == 0) {
        float sacc = 0.f;
        for (int cc = 1; cc < NUM_IDS; ++cc) sacc += red[cc];
        atomicAdd(&ws[WS_PULLACC], sacc);
    }
}

// Final: push + reg + combine. Idempotent (reads finished state, overwrites
// out[0]) -> tripled this round for measurement.
__global__ __launch_bounds__(256) void k5_final(float* __restrict__ ws,
                                                float* __restrict__ out) {
    __shared__ float lmean[NUM_IDS * LPAD];
    __shared__ int   lpres[NUM_IDS];
    __shared__ float red[256];
    __shared__ float red2[256];
    const int t = threadIdx.x;

    if (t < NUM_IDS) {
        float cv = ws[WS_SUMS + NSUM + t];
        lpres[t] = (t > 0 && cv > 0.f) ? 1 : 0;
    }
    for (int j = t; j < NSUM; j += 256) {
        int cc = j >> 5;
        lmean[cc * LPAD + (j & 31)] = ws[WS_SUMS + j] / fmaxf(ws[WS_SUMS + NSUM + cc], 1.f);
    }
    __syncthreads();

    float psum = 0.f;
    for (int pi = t; pi < 2080; pi += 256) {
        int i = 0, rem = pi;
        while (rem >= NUM_IDS - 1 - i) { rem -= NUM_IDS - 1 - i; ++i; }
        int jj = i + 1 + rem;
        if (lpres[i] && lpres[jj]) {
            float d2 = 0.f;
            #pragma unroll
            for (int e = 0; e < EDIM; ++e) {
                float d = lmean[i * LPAD + e] - lmean[jj * LPAD + e];
                d2 += d * d;
            }
            float pd = sqrtf(d2);
            float h = fmaxf(3.0f - pd, 0.f);   // 2*DELTA_PUSH
            psum += h * h;
        }
    }
    float rsum = 0.f;
    if (t < NUM_IDS && lpres[t]) {
        float m2 = 0.f;
        #pragma unroll
        for (int e = 0; e < EDIM; ++e) { float m = lmean[t * LPAD + e]; m2 += m * m; }
        rsum = sqrtf(m2);
    }
    red[t] = psum; red2[t] = rsum;
    __syncthreads();
    for (int sd = 128; sd > 0; sd >>= 1) {
        if (t < sd) { red[t] += red[t + sd]; red2[t] += red2[t + sd]; }
        __syncthreads();
    }
    if (t == 0) {
        int C = 0;
        for (int cc = 1; cc < NUM_IDS; ++cc) C += lpres[cc];
        float Cf = fmaxf((float)C, 1.f);
        long np = (long)C * (C - 1) / 2;
        float push = (np > 0) ? red[0] / (float)np : 0.f;
        float reg  = red2[0] / Cf;
        float total = 0.f;
        if (C > 0) total = ws[WS_PULLACC] / Cf + push + 0.001f * reg;
        out[0] = total;
    }
}

extern "C" void kernel_launch(void* const* d_in, const int* in_sizes, int n_in,
                              void* d_out, int out_size, void* d_ws, size_t ws_size,
                              hipStream_t stream) {
    const float4* emb4 = (const float4*)d_in[0];
    const int* lab = (const int*)d_in[1];
    float* ws = (float*)d_ws;
    float* out = (float*)d_out;
    const int M = in_sizes[1];

    long ws_floats = (long)(ws_size / 4);
    long avail = ws_floats - WS_PART - 64;
    int nb1 = (int)(avail / NTOT);
    if (nb1 > 1024) nb1 = 1024;
    int atomic_mode = (nb1 < 8) ? 1 : 0;
    if (atomic_mode) {
        nb1 = 1024;
        k0_zero<<<dim3(9), dim3(256), 0, stream>>>(ws);
    }
    long str1 = (long)nb1 * 32;
    int nit1 = (int)((M + str1 - 1) / str1);
    nit1 = ((nit1 + 2) / 3) * 3;

    k1_reduce<<<dim3(nb1), dim3(256), 0, stream>>>(emb4, lab, ws, M, nb1, nit1, atomic_mode);
    if (!atomic_mode) {
        // MEASUREMENT: k2 x3 (idempotent). (k2+k5)_dur = (total_now - total_r18)/2 combined with k5 x3 below.
        k2_reduce_partials<<<dim3((NTOT + 31) / 32), dim3(256), 0, stream>>>(ws, nb1);
        k2_reduce_partials<<<dim3((NTOT + 31) / 32), dim3(256), 0, stream>>>(ws, nb1);
        k2_reduce_partials<<<dim3((NTOT + 31) / 32), dim3(256), 0, stream>>>(ws, nb1);
    }
    const int nb4 = 2048;
    k4_pull<<<dim3(nb4), dim3(256), 0, stream>>>(emb4, lab, ws, M, nb4);
    // MEASUREMENT: k5 x3 (idempotent).
    k5_final<<<dim3(1), dim3(256), 0, stream>>>(ws, out);
    k5_final<<<dim3(1), dim3(256), 0, stream>>>(ws, out);
    k5_final<<<dim3(1), dim3(256), 0, stream>>>(ws, out);
}

// Round 20
// 134.538 us; speedup vs baseline: 1.6795x; 1.6795x over previous
//
#include <hip/hip_runtime.h>

#define NUM_IDS 65
#define EDIM 32
#define NSUM (NUM_IDS * EDIM)      // 2080
#define NTOT (NSUM + NUM_IDS)      // 2145
#define LPAD 33                    // mean tile row pad
#define R36 36                     // k1 accum row: 32 sums + count + pad, 144B (16B aligned)
#define CP (NUM_IDS * R36)         // 2340 floats per wave copy

// ws float offsets
#define WS_SUMS    0               // 2145 (2080 sums then 65 counts)
#define WS_PULLACC 2148
#define WS_PART    2176            // [nb1][NTOT]

// pure-VALU cross-lane permute
#define DPPI(x, ctrl) __builtin_amdgcn_update_dpp(0, (x), (ctrl), 0xF, 0xF, true)
// ctrl: 0xB1 quad[1,0,3,2] (^1) | 0x4E quad[2,3,0,1] (^2) | 0x124 row_ror:4

__device__ __forceinline__ void gload4(const float4* p, float4& d) {
    asm volatile("global_load_dwordx4 %0, %1, off" : "=v"(d) : "v"(p));
}
__device__ __forceinline__ void gload1(const int* p, int& d) {
    asm volatile("global_load_dword %0, %1, off" : "=v"(d) : "v"(p));
}
__device__ __forceinline__ void waitN() {      // allow 4 newest loads in flight
    asm volatile("s_waitcnt vmcnt(4)" ::: "memory");
    __builtin_amdgcn_sched_barrier(0);         // rule #18: no hoisting past the wait
}
__device__ __forceinline__ void wait0() {
    asm volatile("s_waitcnt vmcnt(0)" ::: "memory");
    __builtin_amdgcn_sched_barrier(0);
}

__global__ void k0_zero(float* __restrict__ ws) {
    int i = blockIdx.x * 256 + threadIdx.x;
    if (i < NTOT) ws[WS_SUMS + i] = 0.f;
    if (i == 0) ws[WS_PULLACC] = 0.f;
}

// Pass 1 (r13 form, measured ~46us warm): wave-private LDS segment reduction.
__global__ __launch_bounds__(256) void k1_reduce(const float4* __restrict__ emb4,
                                                 const int* __restrict__ lab,
                                                 float* __restrict__ ws,
                                                 int M, int nb1, int nit, int atomic_mode) {
    __shared__ float ls[4 * CP];               // 36.6 KB -> 4 blocks/CU
    const int t = threadIdx.x;
    const int wave = t >> 6, lane = t & 63;
    const int s = lane & 7;                    // point slot
    const int c = lane >> 3;                   // float4 chunk (dims 4c..4c+3)
    float* my = ls + wave * CP;
    for (int j = t; j < 4 * CP; j += 256) ls[j] = 0.f;
    __syncthreads();

    const long Mm1 = (long)M - 1;
    const long STR = (long)nb1 * 32;
    const long p0 = (long)blockIdx.x * 32 + wave * 8 + s;
    const int lp1 = lane + 1;
    int cntreg = 0;
    const int negkey = -64 - s;
    const int e1 = (s ^ 1) < s, e2 = (s ^ 2) < s, e3 = (s ^ 3) < s,
              e4 = (s ^ 4) < s, e5 = (s ^ 5) < s, e6 = (s ^ 6) < s, e7 = (s ^ 7) < s;

    auto ISSUE = [&](int j, int& L, float4& v) {
        long p = p0 + (long)j * STR;
        long pc = p < Mm1 ? p : Mm1;           // clamp: asm loads have no bounds check
        gload1(lab + pc, L);
        gload4(emb4 + pc * 8 + c, v);
    };
    auto PROC = [&](int j, int L, float4 v) {
        const bool inb = (p0 + (long)j * STR) < (long)M;
        const bool act = inb && (L > 0);
        int x0 = act ? L : negkey;             // unique negatives never collide
        int x1 = DPPI(x0, 0xB1);               // key(s^1)
        int x2 = DPPI(x0, 0x4E);               // key(s^2)
        int x3 = DPPI(x1, 0x4E);               // key(s^3)
        int x4 = DPPI(x0, 0x124);              // key(s^4): keys are 8-periodic in lane
        int x5 = DPPI(x1, 0x124);              // key(s^5)
        int x6 = DPPI(x2, 0x124);              // key(s^6)
        int x7 = DPPI(x3, 0x124);              // key(s^7)
        cntreg += (x0 == lp1) + (x1 == lp1) + (x2 == lp1) + (x3 == lp1)
                + (x4 == lp1) + (x5 == lp1) + (x6 == lp1) + (x7 == lp1);
        int ne = (e1 & (x1 == x0)) + (e2 & (x2 == x0)) + (e3 & (x3 == x0))
               + (e4 & (x4 == x0)) + (e5 & (x5 == x0)) + (e6 & (x6 == x0))
               + (e7 & (x7 == x0));            // # earlier slots with same label
        const int off = (act ? L : 0) * R36 + c * 4;
        if (act && ne == 0) {
            float4 o = *(float4*)(my + off);
            o.x += v.x; o.y += v.y; o.z += v.z; o.w += v.w;
            *(float4*)(my + off) = o;
        }
        if (__ballot(act && ne > 0)) {         // rare duplicate labels
            #pragma unroll 1
            for (int r = 1; r < 8; ++r) {
                if (!__ballot(act && ne == r)) break;
                if (act && ne == r) {          // in-order DS sees round r-1 write
                    float4 o = *(float4*)(my + off);
                    o.x += v.x; o.y += v.y; o.z += v.z; o.w += v.w;
                    *(float4*)(my + off) = o;
                }
            }
        }
    };

    int LA, LB, LC; float4 VA, VB, VC;
    ISSUE(0, LA, VA); ISSUE(1, LB, VB);
    for (int i = 0; i < nit; i += 3) {         // nit is a multiple of 3
        ISSUE(i + 2, LC, VC); waitN(); PROC(i, LA, VA);
        ISSUE(i + 3, LA, VA); waitN(); PROC(i + 1, LB, VB);
        ISSUE(i + 4, LB, VB); waitN(); PROC(i + 2, LC, VC);
    }
    wait0();

    my[lp1 * R36 + 32] += (float)cntreg;       // register counts -> rows 1..64
    __syncthreads();

    for (int j = t; j < NTOT; j += 256) {      // combine 4 wave copies
        int off = (j < NSUM) ? ((j >> 5) * R36 + (j & 31))
                             : ((j - NSUM) * R36 + 32);
        float v = ls[off] + ls[CP + off] + ls[2 * CP + off] + ls[3 * CP + off];
        if (atomic_mode) {
            if (v != 0.f) atomicAdd(&ws[WS_SUMS + j], v);
        } else {
            ws[WS_PART + (size_t)blockIdx.x * NTOT + j] = v;
        }
    }
}

// Reduce per-block partials -> SUMS. MLP fix: 8 independent loads per batch
// (measured r19: the rolled loop ran at ~0.35 TB/s, MLP=1, ~25us; batching
// restores ~8x memory-level parallelism).
__global__ __launch_bounds__(256) void k2_reduce_partials(float* __restrict__ ws, int nb1) {
    const int t = threadIdx.x;
    const int jl = t & 31, bl = t >> 5;
    const int j = blockIdx.x * 32 + jl;
    const float* part = ws + WS_PART;
    float acc = 0.f;
    if (j < NTOT) {
        int b = bl;
        for (; b + 56 < nb1; b += 64) {        // 8 rows per batch, stride 8
            float v0 = part[(size_t)(b +  0) * NTOT + j];
            float v1 = part[(size_t)(b +  8) * NTOT + j];
            float v2 = part[(size_t)(b + 16) * NTOT + j];
            float v3 = part[(size_t)(b + 24) * NTOT + j];
            float v4 = part[(size_t)(b + 32) * NTOT + j];
            float v5 = part[(size_t)(b + 40) * NTOT + j];
            float v6 = part[(size_t)(b + 48) * NTOT + j];
            float v7 = part[(size_t)(b + 56) * NTOT + j];
            acc += ((v0 + v1) + (v2 + v3)) + ((v4 + v5) + (v6 + v7));
        }
        for (; b < nb1; b += 8) acc += part[(size_t)b * NTOT + j];
    }
    __shared__ float red[256];
    red[t] = acc;
    __syncthreads();
    for (int sd = 128; sd >= 32; sd >>= 1) {
        if (t < sd) red[t] += red[t + sd];
        __syncthreads();
    }
    if (t < 32) {
        int jj = blockIdx.x * 32 + t;
        if (jj < NTOT) ws[WS_SUMS + jj] = red[t];
    }
    if (blockIdx.x == 0 && t == 0) ws[WS_PULLACC] = 0.f;
}

// Pass 2 (r8 loop form, measured ~60us): builds means+coef locally from SUMS.
__global__ __launch_bounds__(256) void k4_pull(const float4* __restrict__ emb4,
                                               const int* __restrict__ lab,
                                               float* __restrict__ ws,
                                               int M, int nb4) {
    __shared__ float lmean[NUM_IDS * LPAD];
    __shared__ float lcoef[NUM_IDS];
    __shared__ float lpull[NUM_IDS];
    __shared__ float red[NUM_IDS];
    const int t = threadIdx.x;
    for (int j = t; j < NSUM; j += 256) {
        int cc = j >> 5;
        lmean[cc * LPAD + (j & 31)] = ws[WS_SUMS + j] / fmaxf(ws[WS_SUMS + NSUM + cc], 1.f);
    }
    if (t < NUM_IDS) {
        float cv = ws[WS_SUMS + NSUM + t];
        lcoef[t] = (t > 0 && cv > 0.f) ? (1.f / fmaxf(cv, 1.f)) : 0.f;
        lpull[t] = 0.f;
    }
    __syncthreads();

    const int c = t & 7;
    const long stride = (long)nb4 * 32;
    const long start = (long)blockIdx.x * 32 + (t >> 3);

    auto LD = [&](long p, int& L, float4& v) {
        if (p < M) { L = lab[p]; v = emb4[p * 8 + c]; }
        else       { L = 0; v = make_float4(0.f, 0.f, 0.f, 0.f); }
    };
    auto PR = [&](int L, float4 v) {
        float d2 = 0.f;
        if (L > 0) {
            int bse = L * LPAD + c * 4;
            float dx = v.x - lmean[bse + 0];
            float dy = v.y - lmean[bse + 1];
            float dz = v.z - lmean[bse + 2];
            float dw = v.w - lmean[bse + 3];
            d2 = dx * dx + dy * dy + dz * dz + dw * dw;
        }
        d2 += __shfl_xor(d2, 1);
        d2 += __shfl_xor(d2, 2);
        d2 += __shfl_xor(d2, 4);
        if (c == 0 && L > 0 && d2 > 0.f) {
            float dist = sqrtf(d2);
            float h = fmaxf(dist - 0.5f, 0.f);   // DELTA_PULL
            atomicAdd(&lpull[L], h * h);
        }
    };

    int L0, L1;
    float4 v0, v1;
    long pA = start;
    LD(pA, L0, v0);
    while (pA < M) {
        const long pB = pA + stride;
        LD(pB, L1, v1);
        PR(L0, v0);
        const long pA2 = pB + stride;
        LD(pA2, L0, v0);
        PR(L1, v1);
        pA = pA2;
    }
    __syncthreads();
    if (t < NUM_IDS) red[t] = lpull[t] * lcoef[t];
    __syncthreads();
    if (t == 0) {
        float sacc = 0.f;
        for (int cc = 1; cc < NUM_IDS; ++cc) sacc += red[cc];
        atomicAdd(&ws[WS_PULLACC], sacc);
    }
}

// Final: one block computes push + reg (means rebuilt from SUMS) and combines
// with the pull accumulator.
__global__ __launch_bounds__(256) void k5_final(float* __restrict__ ws,
                                                float* __restrict__ out) {
    __shared__ float lmean[NUM_IDS * LPAD];
    __shared__ int   lpres[NUM_IDS];
    __shared__ float red[256];
    __shared__ float red2[256];
    const int t = threadIdx.x;

    if (t < NUM_IDS) {
        float cv = ws[WS_SUMS + NSUM + t];
        lpres[t] = (t > 0 && cv > 0.f) ? 1 : 0;
    }
    for (int j = t; j < NSUM; j += 256) {
        int cc = j >> 5;
        lmean[cc * LPAD + (j & 31)] = ws[WS_SUMS + j] / fmaxf(ws[WS_SUMS + NSUM + cc], 1.f);
    }
    __syncthreads();

    float psum = 0.f;
    for (int pi = t; pi < 2080; pi += 256) {
        int i = 0, rem = pi;
        while (rem >= NUM_IDS - 1 - i) { rem -= NUM_IDS - 1 - i; ++i; }
        int jj = i + 1 + rem;
        if (lpres[i] && lpres[jj]) {
            float d2 = 0.f;
            #pragma unroll
            for (int e = 0; e < EDIM; ++e) {
                float d = lmean[i * LPAD + e] - lmean[jj * LPAD + e];
                d2 += d * d;
            }
            float pd = sqrtf(d2);
            float h = fmaxf(3.0f - pd, 0.f);   // 2*DELTA_PUSH
            psum += h * h;
        }
    }
    float rsum = 0.f;
    if (t < NUM_IDS && lpres[t]) {
        float m2 = 0.f;
        #pragma unroll
        for (int e = 0; e < EDIM; ++e) { float m = lmean[t * LPAD + e]; m2 += m * m; }
        rsum = sqrtf(m2);
    }
    red[t] = psum; red2[t] = rsum;
    __syncthreads();
    for (int sd = 128; sd > 0; sd >>= 1) {
        if (t < sd) { red[t] += red[t + sd]; red2[t] += red2[t + sd]; }
        __syncthreads();
    }
    if (t == 0) {
        int C = 0;
        for (int cc = 1; cc < NUM_IDS; ++cc) C += lpres[cc];
        float Cf = fmaxf((float)C, 1.f);
        long np = (long)C * (C - 1) / 2;
        float push = (np > 0) ? red[0] / (float)np : 0.f;
        float reg  = red2[0] / Cf;
        float total = 0.f;
        if (C > 0) total = ws[WS_PULLACC] / Cf + push + 0.001f * reg;
        out[0] = total;
    }
}

extern "C" void kernel_launch(void* const* d_in, const int* in_sizes, int n_in,
                              void* d_out, int out_size, void* d_ws, size_t ws_size,
                              hipStream_t stream) {
    const float4* emb4 = (const float4*)d_in[0];
    const int* lab = (const int*)d_in[1];
    float* ws = (float*)d_ws;
    float* out = (float*)d_out;
    const int M = in_sizes[1];

    long ws_floats = (long)(ws_size / 4);
    long avail = ws_floats - WS_PART - 64;
    int nb1 = (int)(avail / NTOT);
    if (nb1 > 1024) nb1 = 1024;
    int atomic_mode = (nb1 < 8) ? 1 : 0;
    if (atomic_mode) {
        nb1 = 1024;
        k0_zero<<<dim3(9), dim3(256), 0, stream>>>(ws);
    }
    long str1 = (long)nb1 * 32;
    int nit1 = (int)((M + str1 - 1) / str1);
    nit1 = ((nit1 + 2) / 3) * 3;

    k1_reduce<<<dim3(nb1), dim3(256), 0, stream>>>(emb4, lab, ws, M, nb1, nit1, atomic_mode);
    if (!atomic_mode)
        k2_reduce_partials<<<dim3((NTOT + 31) / 32), dim3(256), 0, stream>>>(ws, nb1);
    const int nb4 = 2048;
    k4_pull<<<dim3(nb4), dim3(256), 0, stream>>>(emb4, lab, ws, M, nb4);
    k5_final<<<dim3(1), dim3(256), 0, stream>>>(ws, out);
}